// Round 1
// baseline (241.391 us; speedup 1.0000x reference)
//
#include <hip/hip_runtime.h>
#include <math.h>

typedef unsigned long long u64;
typedef unsigned int u32;

#define BN 8
#define NA_T 9
#define NPOS 2500
#define FHW 50
#define N_ANCH 22500
#define NG 20
#define PRE 2000
#define POST 300
#define TOTAL (BN * N_ANCH)      // 180000
#define HALF_RNG 90000u

#define NB_LAB 704    // 88 * 8 merged prop+label blocks
#define NB_GTB 160    // 8 * 20

// ---------------- device helpers ----------------

__device__ __forceinline__ void anchor_dims(int d, float& w, float& h) {
    const double scl[3] = {8.0, 16.0, 32.0};
    const double rat[3] = {0.5, 1.0, 2.0};
    double s = 16.0 * scl[d / 3];
    double r = rat[d % 3];
    w = (float)(s * sqrt(r));
    h = (float)(s * sqrt(1.0 / r));
}

__device__ __forceinline__ void anchor_corners(int n, float& x1, float& y1, float& x2, float& y2) {
    int d = n / NPOS, k = n % NPOS;
    float cx = (float)(8 + 16 * (k / FHW));
    float cy = (float)(8 + 16 * (k % FHW));
    float w, h; anchor_dims(d, w, h);
    x1 = cx - 0.5f * w; y1 = cy - 0.5f * h;
    x2 = cx + 0.5f * w; y2 = cy + 0.5f * h;
}

__device__ __forceinline__ float iou_f(float ax1, float ay1, float ax2, float ay2,
                                       float bx1, float by1, float bx2, float by2) {
    float tlx = fmaxf(ax1, bx1), tly = fmaxf(ay1, by1);
    float brx = fminf(ax2, bx2), bry = fminf(ay2, by2);
    float wx = fmaxf(brx - tlx, 0.0f);
    float wy = fmaxf(bry - tly, 0.0f);
    float inter = wx * wy;
    float a1 = (ax2 - ax1) * (ay2 - ay1);
    float a2 = (bx2 - bx1) * (by2 - by1);
    float den = fmaxf(a1 + a2 - inter, 1e-8f);
    return inter / den;
}

__device__ __forceinline__ unsigned int f32_sort_asc(float f) {
    unsigned int u = __float_as_uint(f);
    return (u & 0x80000000u) ? ~u : (u | 0x80000000u);
}

#define TF_R(r) { x0 += x1; x1 = ((x1 << r) | (x1 >> (32 - r))); x1 ^= x0; }
__device__ __forceinline__ unsigned int threefry_bits(unsigned int j) {
    unsigned int i = (j < HALF_RNG) ? j : j - HALF_RNG;
    unsigned int x0 = i, x1 = i + HALF_RNG;
    const unsigned int ks0 = 0u, ks1 = 42u, ks2 = 0x1BD11BDAu ^ 0u ^ 42u;
    x0 += ks0; x1 += ks1;
    TF_R(13) TF_R(15) TF_R(26) TF_R(6)
    x0 += ks1; x1 += ks2 + 1u;
    TF_R(17) TF_R(29) TF_R(16) TF_R(24)
    x0 += ks2; x1 += ks0 + 2u;
    TF_R(13) TF_R(15) TF_R(26) TF_R(6)
    x0 += ks0; x1 += ks1 + 3u;
    TF_R(17) TF_R(29) TF_R(16) TF_R(24)
    x0 += ks1; x1 += ks2 + 4u;
    TF_R(13) TF_R(15) TF_R(26) TF_R(6)
    x0 += ks2; x1 += ks0 + 5u;
    return (j < HALF_RNG) ? x0 : x1;
}

__device__ __forceinline__ float smooth_l1(float d) {
    float ad = fabsf(d);
    return (ad < (float)(1.0 / 9.0)) ? (4.5f * d) * d : (ad - (float)(0.5 / 9.0));
}

// block-wide u64 sum broadcast. sred has 16 slots (nwaves<=16).
__device__ __forceinline__ u64 block_sum_u64(u64 v, u64* sred, int nwaves) {
    for (int o = 32; o >= 1; o >>= 1) v += __shfl_down(v, o);
    int wid = threadIdx.x >> 6;
    if ((threadIdx.x & 63) == 0) sred[wid] = v;
    __syncthreads();
    u64 s = 0;
    for (int i = 0; i < nwaves; ++i) s += sred[i];
    return s;
}

// After hist[0..nb) filled: find bin containing rank `remaining` (1-indexed) and
// residual rank. Wave 0 computes; result in s_out[0]=digit, s_out[1]=remaining.
// All threads call (barrier inside). nb multiple of 64.
__device__ __forceinline__ void hist_pick(const u32* hist, int nb,
                                          u32 remaining, u32* s_out) {
    if (threadIdx.x < 64) {
        int lane = threadIdx.x;
        int bpl = nb >> 6;
        int base = lane * bpl;
        u32 s = 0;
        for (int i = 0; i < bpl; ++i) s += hist[base + i];
        u32 p = s;
        for (int o = 1; o < 64; o <<= 1) {
            u32 t = __shfl_up(p, o);
            if (lane >= o) p += t;
        }
        u32 e = p - s;
        if (e < remaining && remaining <= p) {
            u32 cum = e;
            for (int i = 0; i < bpl; ++i) {
                u32 h = hist[base + i];
                if (cum + h >= remaining) {
                    s_out[0] = (u32)(base + i);
                    s_out[1] = remaining - cum;
                    break;
                }
                cum += h;
            }
        }
    }
    __syncthreads();
}

// warp-aggregated push: returns slot if pred else -1. All active lanes call together.
__device__ __forceinline__ int wave_push(u32* ctr, bool pred) {
    u64 m = __ballot(pred);
    if (m == 0) return -1;
    int lane = threadIdx.x & 63;
    int leader = __ffsll((long long)m) - 1;
    u32 base = 0;
    if (lane == leader) base = atomicAdd(ctr, (u32)__popcll(m));
    base = (u32)__shfl((int)base, leader);
    return pred ? (int)(base + __popcll(m & ((1ull << lane) - 1ull))) : -1;
}

// ---------------- k_a: keys + packed(label,argmax,mant) + hists | gt_best ----------------

__global__ void k_a(const float* __restrict__ cls, const float* __restrict__ gt,
                    u32* __restrict__ kd_g, u32* __restrict__ samp,
                    int* __restrict__ gt_best,
                    u32* __restrict__ hist0, u32* __restrict__ histP,
                    u32* __restrict__ histN) {
    __shared__ float4 g[NG];
    __shared__ float sv[256];
    __shared__ int si[256];
    int bid = blockIdx.x;

    if (bid < NB_LAB) {
        int b = bid / 88, bx = bid % 88;
        if (threadIdx.x < NG) g[threadIdx.x] = ((const float4*)gt)[b * NG + threadIdx.x];
        __syncthreads();
        int n = bx * 256 + threadIdx.x;
        if (n >= N_ANCH) return;
        float ax1, ay1, ax2, ay2; anchor_corners(n, ax1, ay1, ax2, ay2);
        float best = -1.0f; int bi = 0;
        for (int gi = 0; gi < NG; ++gi) {
            float4 G = g[gi];
            float v = iou_f(G.x, G.y, G.z, G.w, ax1, ay1, ax2, ay2);
            if (v > best) { best = v; bi = gi; }  // first-max
        }
        int lab = -1;
        if (best < 0.3f) lab = 0;
        if (best >= 0.7f) lab = 1;
        bool inside = (ax1 >= 0.0f && ay1 >= 0.0f && ax2 <= 800.0f && ay2 <= 800.0f);
        // enc: 0 -> -1(outside), 1 -> 0, 2 -> 1, 3 -> -1(inside, immune to gt_best)
        int enc = inside ? 3 : (lab + 1);
        int t = b * N_ANCH + n;
        u32 mant = threefry_bits((u32)t) >> 9;   // 23-bit uniform mantissa
        samp[t] = (mant << 9) | ((u32)bi << 4) | (u32)enc;
        if (enc == 2) atomicAdd(&histP[b * 2048 + (mant >> 12)], 1u);
        if (enc == 1) atomicAdd(&histN[b * 2048 + (mant >> 12)], 1u);
        int a = n % NA_T, hw = n / NA_T;
        float score = cls[((size_t)b * 18 + 9 + a) * NPOS + hw];
        u32 kd = ~f32_sort_asc(score);           // asc key: smaller = higher score
        kd_g[t] = kd;
        atomicAdd(&hist0[b * 2048 + (kd >> 21)], 1u);
    } else {
        int gid = bid - NB_LAB;
        int b = gid / NG, gi = gid % NG;
        float4 G = ((const float4*)gt)[b * NG + gi];
        float best = -1.0f; int bidx = N_ANCH;
        for (int d = 0; d < 9; ++d) {
            float w, h; anchor_dims(d, w, h);
            for (int k = threadIdx.x; k < NPOS; k += 256) {
                float cx = (float)(8 + 16 * (k / FHW));
                float cy = (float)(8 + 16 * (k % FHW));
                float x1 = cx - 0.5f * w, y1 = cy - 0.5f * h;
                float x2 = cx + 0.5f * w, y2 = cy + 0.5f * h;
                float v = iou_f(G.x, G.y, G.z, G.w, x1, y1, x2, y2);
                if (v > best) { best = v; bidx = d * NPOS + k; }
            }
        }
        sv[threadIdx.x] = best; si[threadIdx.x] = bidx;
        __syncthreads();
        for (int s = 128; s > 0; s >>= 1) {
            if (threadIdx.x < s) {
                float v2 = sv[threadIdx.x + s]; int i2 = si[threadIdx.x + s];
                if (v2 > sv[threadIdx.x] || (v2 == sv[threadIdx.x] && i2 < si[threadIdx.x])) {
                    sv[threadIdx.x] = v2; si[threadIdx.x] = i2;
                }
            }
            __syncthreads();
        }
        if (threadIdx.x == 0) gt_best[gid] = si[0];
    }
}

// ---------------- k_c: blocks 0-7 topk+NMS | blocks 8-15 sample+loss+final ----------------

__global__ void __launch_bounds__(1024) k_c(
    const u32* __restrict__ kd_g, const u32* __restrict__ samp,
    const int* __restrict__ gt_best, const u32* __restrict__ hist0,
    const u32* __restrict__ histP, const u32* __restrict__ histN,
    const float* __restrict__ pred, const float* __restrict__ cls,
    const float* __restrict__ gt, float* __restrict__ out,
    double* __restrict__ acc, int* __restrict__ cnt_out, u32* __restrict__ done)
{
    int tid = threadIdx.x;
    int lane = tid & 63, wid = tid >> 6;

    __shared__ u32 histA[4096];
    __shared__ u64 poolB[2048];     // topk: bin candidates, then (x1,y1) | sample: bitmap + sred
    __shared__ u64 sk[2048];        // topk: keys/sort, then (x2,y2) | sample: bufP/bufN
    __shared__ float4 accb[POST];
    __shared__ u64 Smat[64];
    __shared__ u64 wsup[16];
    __shared__ u32 s_out[2];
    __shared__ u32 s_cnt, s_cnt2;
    __shared__ int s_scount;
    __shared__ int sgb[NG];
    __shared__ u64 sTp, sTn;
    if (tid < 2) s_out[tid] = 0;

    if (blockIdx.x < BN) {
        // ================== TOPK + NMS (batch b) ==================
        int b = blockIdx.x;
        const u32* kb = kd_g + (size_t)b * N_ANCH;

        // boundary bin from precomputed global hist (2048 bins over kd>>21)
        for (int i = tid; i < 2048; i += 1024) histA[i] = hist0[b * 2048 + i];
        __syncthreads();
        hist_pick(histA, 2048, PRE, s_out);
        u32 d0 = s_out[0], r0 = s_out[1];
        u32 bincnt = histA[d0];
        bool fast = bincnt <= 2048;
        __syncthreads();

        for (int i = tid; i < 2048; i += 1024) sk[i] = ~0ull;
        if (tid == 0) { s_cnt = 0; s_cnt2 = 0; }
        __syncthreads();

        // ONE scan: below-bin keys -> sk, boundary-bin keys -> poolB
        for (int c = 0; c < 22; ++c) {
            int n = tid + c * 1024;
            bool valid = n < N_ANCH;
            u32 kd = valid ? kb[n] : 0xFFFFFFFFu;
            u64 kk = (((u64)kd) << 15) | (u32)(valid ? n : 0);
            u32 topb = kd >> 21;
            int ps = wave_push(&s_cnt, valid && topb < d0);
            if (ps >= 0) sk[ps] = kk;
            int pb = wave_push(&s_cnt2, valid && fast && topb == d0);
            if (pb >= 0 && pb < 2048) poolB[pb] = kk;
        }
        __syncthreads();
        int bc = (int)s_cnt2;

        // refine exact 47-bit threshold: 3 x 12-bit passes (over LDS bin buffer,
        // or full-array fallback if the bin overflowed the buffer)
        u64 prefix = ((u64)d0) << 36;
        u32 remaining = r0;
        for (int p = 0; p < 3; ++p) {
            int sh = 24 - 12 * p;
            for (int i = tid; i < 4096; i += 1024) histA[i] = 0;
            __syncthreads();
            u64 himask = ~((1ull << (sh + 12)) - 1);
            if (fast) {
                for (int i = tid; i < bc; i += 1024) {
                    u64 kk = poolB[i];
                    if ((kk & himask) == prefix)
                        atomicAdd(&histA[(u32)((kk >> sh) & 4095ull)], 1u);
                }
            } else {
                for (int c = 0; c < 22; ++c) {
                    int n = tid + c * 1024;
                    if (n < N_ANCH) {
                        u64 kk = (((u64)kb[n]) << 15) | (u32)n;
                        if ((kk & himask) == prefix)
                            atomicAdd(&histA[(u32)((kk >> sh) & 4095ull)], 1u);
                    }
                }
            }
            __syncthreads();
            hist_pick(histA, 4096, remaining, s_out);
            prefix |= ((u64)s_out[0]) << sh;
            remaining = s_out[1];
            __syncthreads();
        }
        u64 T = prefix;   // exact: {key <= T} has size 2000

        // append bin-selected keys; sk now holds exactly 2000 keys + ~0 filler
        if (fast) {
            for (int i = tid; i < bc; i += 1024) {
                u64 kk = poolB[i];
                int ps = wave_push(&s_cnt, kk <= T);
                if (ps >= 0) sk[ps] = kk;
            }
        } else {
            for (int c = 0; c < 22; ++c) {
                int n = tid + c * 1024;
                bool valid = n < N_ANCH;
                u32 kd = valid ? kb[n] : 0xFFFFFFFFu;
                u64 kk = (((u64)kd) << 15) | (u32)(valid ? n : 0);
                int ps = wave_push(&s_cnt, valid && (kd >> 21) == d0 && kk <= T);
                if (ps >= 0) sk[ps] = kk;
            }
        }
        __syncthreads();

        // bitonic sort 2048 in LDS
        for (int k = 2; k <= 2048; k <<= 1) {
            for (int j = k >> 1; j > 0; j >>= 1) {
                for (int i = tid; i < 2048; i += 1024) {
                    int l = i ^ j;
                    if (l > i) {
                        u64 ai = sk[i], al = sk[l];
                        bool up = ((i & k) == 0);
                        if ((ai > al) == up) { sk[i] = al; sk[l] = ai; }
                    }
                }
                __syncthreads();
            }
        }

        // recompute proposal boxes for the sorted 2000 (bit-identical math)
        float2* bl = (float2*)poolB;
        float2* bh = (float2*)sk;
        for (int i = tid; i < 2048; i += 1024) {
            float2 lo = make_float2(0.f, 0.f), hi = make_float2(0.f, 0.f);
            if (i < PRE) {
                int n = (int)(sk[i] & 0x7fffu);
                float ax1, ay1, ax2, ay2; anchor_corners(n, ax1, ay1, ax2, ay2);
                float acx = (ax1 + ax2) * 0.5f, acy = (ay1 + ay2) * 0.5f;
                float aw = ax2 - ax1, ah = ay2 - ay1;
                int a = n % NA_T, hw = n / NA_T;
                const float* pb = pred + (size_t)b * 36 * NPOS;
                float dx = pb[(4 * a + 0) * NPOS + hw];
                float dy = pb[(4 * a + 1) * NPOS + hw];
                float dw = pb[(4 * a + 2) * NPOS + hw];
                float dh = pb[(4 * a + 3) * NPOS + hw];
                float px = acx + dx * aw, py = acy + dy * ah;
                float pw = aw * expf(dw), ph = ah * expf(dh);
                float x1 = px - 0.5f * pw, y1 = py - 0.5f * ph;
                float x2 = px + 0.5f * pw, y2 = py + 0.5f * ph;
                x1 = fminf(fmaxf(x1, 0.0f), 799.0f);
                y1 = fminf(fmaxf(y1, 0.0f), 799.0f);
                x2 = fminf(fmaxf(x2, 0.0f), 799.0f);
                y2 = fminf(fmaxf(y2, 0.0f), 799.0f);
                lo = make_float2(x1, y1); hi = make_float2(x2, y2);
            }
            bl[i] = lo; bh[i] = hi;
        }
        if (tid == 0) s_scount = 0;
        __syncthreads();

        // ---- on-the-fly greedy NMS ----
        for (int c = 0; c < 32; ++c) {
            int A = s_scount;
            int base = c * 64;
            float2 clo = bl[base + lane], chi = bh[base + lane];
            bool sup = false;
            for (int a = wid; a < A; a += 16) {
                float4 ab = accb[a];
                sup |= iou_f(ab.x, ab.y, ab.z, ab.w, clo.x, clo.y, chi.x, chi.y) > 0.7f;
            }
            u64 bal = __ballot(sup);
            if (lane == 0) wsup[wid] = bal;
            #pragma unroll
            for (int q = 0; q < 4; ++q) {
                int o = wid * 4 + q;
                float2 olo = bl[base + o], ohi = bh[base + o];
                bool hit = iou_f(olo.x, olo.y, ohi.x, ohi.y, clo.x, clo.y, chi.x, chi.y) > 0.7f;
                u64 m = __ballot(hit);
                if (lane == 0) Smat[o] = m;
            }
            __syncthreads();
            if (wid == 0) {
                u64 supmask = 0;
                #pragma unroll
                for (int i2 = 0; i2 < 16; ++i2) supmask |= wsup[i2];
                int jmax = min(64, PRE - base);
                u64 valid = (jmax >= 64) ? ~0ull : ((1ull << jmax) - 1ull);
                u64 live = (~supmask) & valid;
                int count = A;
                while (live && count < POST) {
                    int i = __ffsll((long long)live) - 1;
                    if (lane == 0) {
                        float2 lo2 = bl[base + i], hi2 = bh[base + i];
                        accb[count] = make_float4(lo2.x, lo2.y, hi2.x, hi2.y);
                    }
                    u64 sm = Smat[i];
                    live &= ~sm;
                    live &= ~(1ull << i);
                    count++;
                }
                if (lane == 0) s_scount = count;
            }
            __syncthreads();
            if (s_scount >= POST) break;
        }
        int cntk = s_scount;
        for (int s = tid; s < POST; s += 1024) {
            float4 v = make_float4(0.f, 0.f, 0.f, 0.f);
            if (s < cntk) {
                float4 p = accb[s];
                v = make_float4(floorf(p.x), floorf(p.y), floorf(p.z), floorf(p.w));
            }
            ((float4*)out)[(size_t)b * POST + s] = v;
        }
    } else {
        // ================== SAMPLE + LOSS (batch b) ==================
        int b = blockIdx.x - BN;
        u32* bitmap = (u32*)poolB;        // 704 u32 = 2816 B
        u64* sred   = poolB + 512;        // byte offset 4096, clear of bitmap
        u32* hP = histA;                  // 2048
        u32* hN = histA + 2048;           // 2048
        u64* bufP = sk;                   // 1024
        u64* bufN = sk + 1024;            // 1024

        for (int i = tid; i < 704; i += 1024) bitmap[i] = 0;
        if (tid < NG) sgb[tid] = gt_best[b * NG + tid];
        for (int i = tid; i < 2048; i += 1024) {
            hP[i] = histP[b * 2048 + i];
            hN[i] = histN[b * 2048 + i];
        }
        __syncthreads();
        if (tid < NG) {
            int gn = sgb[tid];
            atomicOr(&bitmap[gn >> 5], 1u << (gn & 31));
            bool dup = false;
            for (int j = 0; j < tid; ++j) dup |= (sgb[j] == gn);
            if (!dup) {
                // apply gt_best promotion to hist copies (rank-exact correction)
                u32 sp = samp[(size_t)b * N_ANCH + gn];
                int enc = (int)(sp & 3u);
                if (enc != 3) {               // inside anchors stay -1
                    if (enc != 2) atomicAdd(&hP[sp >> 21], 1u);
                    if (enc == 1) atomicSub(&hN[sp >> 21], 1u);
                }
            }
        }
        __syncthreads();

        u32 aP = 0, aN = 0;
        for (int i = tid; i < 2048; i += 1024) { aP += hP[i]; aN += hN[i]; }
        u64 packed = block_sum_u64(((u64)aP << 32) | (u64)aN, sred, 16);
        int cpt = (int)(packed >> 32), ctot = (int)(packed & 0xffffffffu);
        int np = min(cpt, 128), nn = min(ctot, 256 - np);

        bool needP = cpt > np, needN = ctot > nn;
        u32 dP = 0, remP = 0, dN = 0, remN = 0;
        if (needP) {
            hist_pick(hP, 2048, (u32)np, s_out);
            dP = s_out[0]; remP = s_out[1];
            __syncthreads();
        }
        if (needN) {
            hist_pick(hN, 2048, (u32)nn, s_out);
            dN = s_out[0]; remN = s_out[1];
            __syncthreads();
        }

        if (tid == 0) { s_cnt = 0; s_cnt2 = 0; }
        __syncthreads();

        // ONE scan: gather boundary-bin candidates for pos and neg
        const u32* sb = samp + (size_t)b * N_ANCH;
        for (int c = 0; c < 22; ++c) {
            int n = tid + c * 1024;
            bool valid = n < N_ANCH;
            u32 sp = valid ? sb[n] : 0u;
            int enc = (int)(sp & 3u);
            bool bm = valid && ((bitmap[n >> 5] >> (n & 31)) & 1u);
            int l = (enc == 3) ? -1 : (bm ? 1 : enc - 1);
            u64 kk = (((u64)(sp >> 9)) << 15) | (u32)(valid ? n : 0);
            int pp = wave_push(&s_cnt, valid && needP && l == 1 && (sp >> 21) == dP);
            if (pp >= 0 && pp < 1024) bufP[pp] = kk;
            int pn = wave_push(&s_cnt2, valid && needN && l == 0 && (sp >> 21) == dN);
            if (pn >= 0 && pn < 1024) bufN[pn] = kk;
        }
        __syncthreads();

        // tiny exact rank-select within each boundary bin (O(cnt^2), cnt ~ 10)
        if (needP) {
            int cnt = min((int)s_cnt, 1024);
            for (int i = tid; i < cnt; i += 1024) {
                u64 ki = bufP[i]; int rank = 0;
                for (int j = 0; j < cnt; ++j) rank += (bufP[j] < ki);
                if (rank == (int)remP - 1) sTp = ki;
            }
        }
        if (needN) {
            int cnt = min((int)s_cnt2, 1024);
            for (int i = tid; i < cnt; i += 1024) {
                u64 ki = bufN[i]; int rank = 0;
                for (int j = 0; j < cnt; ++j) rank += (bufN[j] < ki);
                if (rank == (int)remN - 1) sTn = ki;
            }
        }
        __syncthreads();
        u64 Tp = needP ? sTp : ~0ull;
        u64 Tn = needN ? sTn : ~0ull;

        // loss over selected samples
        double lcls = 0.0, lbox = 0.0;
        #pragma unroll
        for (int c = 0; c < 22; ++c) {
            int n = tid + c * 1024;
            if (n >= N_ANCH) continue;
            u32 sp = sb[n];
            int enc = (int)(sp & 3u);
            bool bm = (bitmap[n >> 5] >> (n & 31)) & 1u;
            int l = (enc == 3) ? -1 : (bm ? 1 : enc - 1);
            if (l < 0) continue;
            u64 kk = (((u64)(sp >> 9)) << 15) | (u32)n;
            int lab = -1;
            if (l == 1) { if (kk <= Tp) lab = 1; }
            else        { if (kk <= Tn) lab = 0; }
            if (lab < 0) continue;
            int a = n % NA_T, hw = n / NA_T;
            float l0 = cls[((size_t)b * 18 + 2 * a + 0) * NPOS + hw];
            float l1 = cls[((size_t)b * 18 + 2 * a + 1) * NPOS + hw];
            float m = fmaxf(l0, l1);
            float s0 = l0 - m, s1 = l1 - m;
            float lse = logf(expf(s0) + expf(s1));
            lcls += (double)(-((lab ? s1 : s0) - lse));
            if (lab == 1) {
                const float* pb = pred + (size_t)b * 36 * NPOS;
                float dx = pb[(4 * a + 0) * NPOS + hw];
                float dy = pb[(4 * a + 1) * NPOS + hw];
                float dw = pb[(4 * a + 2) * NPOS + hw];
                float dh = pb[(4 * a + 3) * NPOS + hw];
                float ax1, ay1, ax2, ay2; anchor_corners(n, ax1, ay1, ax2, ay2);
                float acx = (ax1 + ax2) * 0.5f, acy = (ay1 + ay2) * 0.5f;
                float aw = ax2 - ax1, ah = ay2 - ay1;
                float4 G = ((const float4*)gt)[b * NG + ((sp >> 4) & 31u)];
                float gcx = (G.x + G.z) * 0.5f, gcy = (G.y + G.w) * 0.5f;
                float gw = G.z - G.x, gh = G.w - G.y;
                float t0 = (gcx - acx) / aw, t1 = (gcy - acy) / ah;
                float t2 = logf(gw / aw), t3 = logf(gh / ah);
                lbox += (double)(smooth_l1(dx - t0) + smooth_l1(dy - t1) +
                                 smooth_l1(dw - t2) + smooth_l1(dh - t3));
            }
        }
        for (int o = 32; o >= 1; o >>= 1) {
            lcls += __shfl_down(lcls, o);
            lbox += __shfl_down(lbox, o);
        }
        if ((tid & 63) == 0) {
            atomicAdd(&acc[0], lcls);
            atomicAdd(&acc[1], lbox);
        }
        if (tid == 0) cnt_out[b] = np + nn;
        __syncthreads();

        if (tid == 0) {
            __threadfence();
            u32 r = atomicAdd(done, 1u);
            if (r == BN - 1) {
                __threadfence();
                volatile double* va = (volatile double*)acc;
                volatile int* vc = (volatile int*)cnt_out;
                double a0 = va[0], a1 = va[1];
                int total = 0, c0 = 0;
                for (int bb = 0; bb < BN; ++bb) {
                    int v = vc[bb];
                    total += v;
                    if (bb == 0) c0 = v;
                }
                out[BN * POST * 4 + 0] = (float)(a1 / (double)max(c0, 1));     // bbox_loss
                out[BN * POST * 4 + 1] = (float)(a0 / (double)max(total, 1));  // cls_loss
            }
        }
    }
}

// ---------------- launch ----------------

extern "C" void kernel_launch(void* const* d_in, const int* in_sizes, int n_in,
                              void* d_out, int out_size, void* d_ws, size_t ws_size,
                              hipStream_t stream) {
    (void)in_sizes; (void)n_in; (void)out_size; (void)ws_size;
    const float* pred = (const float*)d_in[0];   // (8,36,50,50)
    const float* cls  = (const float*)d_in[1];   // (8,18,50,50)
    const float* gt   = (const float*)d_in[2];   // (8,20,4)
    float* out = (float*)d_out;                  // 9600 boxes + 2 losses

    char* w = (char*)d_ws;
    size_t off = 0;
    auto take = [&](size_t bytes) { void* p = w + off; off += (bytes + 255) & ~(size_t)255; return p; };
    // zero-region first (single memset covers hists + acc + done)
    size_t z0 = off;
    u32* hist0   = (u32*)take((size_t)BN * 2048 * 4);    // 64 KB
    u32* histP   = (u32*)take((size_t)BN * 2048 * 4);    // 64 KB
    u32* histN   = (u32*)take((size_t)BN * 2048 * 4);    // 64 KB
    double* acc  = (double*)take(2 * 8);
    u32* done    = (u32*)take(4);
    size_t z1 = off;
    u32* kd_g    = (u32*)take((size_t)TOTAL * 4);        // 720 KB
    u32* samp    = (u32*)take((size_t)TOTAL * 4);        // 720 KB (mant|argmax|label)
    int* gt_best = (int*)take((size_t)BN * NG * 4);
    int* cnt_out = (int*)take(BN * 4);

    hipMemsetAsync(w + z0, 0, z1 - z0, stream);
    k_a<<<NB_LAB + NB_GTB, 256, 0, stream>>>(cls, gt, kd_g, samp, gt_best,
                                             hist0, histP, histN);
    k_c<<<2 * BN, 1024, 0, stream>>>(kd_g, samp, gt_best, hist0, histP, histN,
                                     pred, cls, gt, out, acc, cnt_out, done);
}

// Round 2
// 177.792 us; speedup vs baseline: 1.3577x; 1.3577x over previous
//
#include <hip/hip_runtime.h>
#include <math.h>

typedef unsigned long long u64;
typedef unsigned int u32;

#define BN 8
#define NA_T 9
#define NPOS 2500
#define FHW 50
#define N_ANCH 22500
#define NG 20
#define PRE 2000
#define POST 300
#define TOTAL (BN * N_ANCH)      // 180000
#define HALF_RNG 90000u

#define NB_LAB 704    // 88 * 8 merged prop+label blocks
#define NB_GTB 160    // 8 * 20

// ---------------- device helpers ----------------

__device__ __forceinline__ void anchor_dims(int d, float& w, float& h) {
    const double scl[3] = {8.0, 16.0, 32.0};
    const double rat[3] = {0.5, 1.0, 2.0};
    double s = 16.0 * scl[d / 3];
    double r = rat[d % 3];
    w = (float)(s * sqrt(r));
    h = (float)(s * sqrt(1.0 / r));
}

__device__ __forceinline__ void anchor_corners(int n, float& x1, float& y1, float& x2, float& y2) {
    int d = n / NPOS, k = n % NPOS;
    float cx = (float)(8 + 16 * (k / FHW));
    float cy = (float)(8 + 16 * (k % FHW));
    float w, h; anchor_dims(d, w, h);
    x1 = cx - 0.5f * w; y1 = cy - 0.5f * h;
    x2 = cx + 0.5f * w; y2 = cy + 0.5f * h;
}

__device__ __forceinline__ float iou_f(float ax1, float ay1, float ax2, float ay2,
                                       float bx1, float by1, float bx2, float by2) {
    float tlx = fmaxf(ax1, bx1), tly = fmaxf(ay1, by1);
    float brx = fminf(ax2, bx2), bry = fminf(ay2, by2);
    float wx = fmaxf(brx - tlx, 0.0f);
    float wy = fmaxf(bry - tly, 0.0f);
    float inter = wx * wy;
    float a1 = (ax2 - ax1) * (ay2 - ay1);
    float a2 = (bx2 - bx1) * (by2 - by1);
    float den = fmaxf(a1 + a2 - inter, 1e-8f);
    return inter / den;
}

__device__ __forceinline__ unsigned int f32_sort_asc(float f) {
    unsigned int u = __float_as_uint(f);
    return (u & 0x80000000u) ? ~u : (u | 0x80000000u);
}

#define TF_R(r) { x0 += x1; x1 = ((x1 << r) | (x1 >> (32 - r))); x1 ^= x0; }
__device__ __forceinline__ unsigned int threefry_bits(unsigned int j) {
    unsigned int i = (j < HALF_RNG) ? j : j - HALF_RNG;
    unsigned int x0 = i, x1 = i + HALF_RNG;
    const unsigned int ks0 = 0u, ks1 = 42u, ks2 = 0x1BD11BDAu ^ 0u ^ 42u;
    x0 += ks0; x1 += ks1;
    TF_R(13) TF_R(15) TF_R(26) TF_R(6)
    x0 += ks1; x1 += ks2 + 1u;
    TF_R(17) TF_R(29) TF_R(16) TF_R(24)
    x0 += ks2; x1 += ks0 + 2u;
    TF_R(13) TF_R(15) TF_R(26) TF_R(6)
    x0 += ks0; x1 += ks1 + 3u;
    TF_R(17) TF_R(29) TF_R(16) TF_R(24)
    x0 += ks1; x1 += ks2 + 4u;
    TF_R(13) TF_R(15) TF_R(26) TF_R(6)
    x0 += ks2; x1 += ks0 + 5u;
    return (j < HALF_RNG) ? x0 : x1;
}

__device__ __forceinline__ float smooth_l1(float d) {
    float ad = fabsf(d);
    return (ad < (float)(1.0 / 9.0)) ? (4.5f * d) * d : (ad - (float)(0.5 / 9.0));
}

__device__ __forceinline__ u64 shflx64(u64 v, int m) {
    u32 lo = (u32)v, hi = (u32)(v >> 32);
    lo = (u32)__shfl_xor((int)lo, m);
    hi = (u32)__shfl_xor((int)hi, m);
    return (((u64)hi) << 32) | lo;
}

__device__ __forceinline__ u64 shfl64(u64 v, int src) {
    u32 lo = (u32)v, hi = (u32)(v >> 32);
    lo = (u32)__shfl((int)lo, src);
    hi = (u32)__shfl((int)hi, src);
    return (((u64)hi) << 32) | lo;
}

// block-wide u64 sum broadcast. sred has 16 slots (nwaves<=16).
__device__ __forceinline__ u64 block_sum_u64(u64 v, u64* sred, int nwaves) {
    for (int o = 32; o >= 1; o >>= 1) v += __shfl_down(v, o);
    int wid = threadIdx.x >> 6;
    if ((threadIdx.x & 63) == 0) sred[wid] = v;
    __syncthreads();
    u64 s = 0;
    for (int i = 0; i < nwaves; ++i) s += sred[i];
    return s;
}

// After hist[0..nb) filled: find bin containing rank `remaining` (1-indexed) and
// residual rank. Wave 0 computes; result in s_out[0]=digit, s_out[1]=remaining.
// All threads call (barrier inside). nb multiple of 64.
__device__ __forceinline__ void hist_pick(const u32* hist, int nb,
                                          u32 remaining, u32* s_out) {
    if (threadIdx.x < 64) {
        int lane = threadIdx.x;
        int bpl = nb >> 6;
        int base = lane * bpl;
        u32 s = 0;
        for (int i = 0; i < bpl; ++i) s += hist[base + i];
        u32 p = s;
        for (int o = 1; o < 64; o <<= 1) {
            u32 t = __shfl_up(p, o);
            if (lane >= o) p += t;
        }
        u32 e = p - s;
        if (e < remaining && remaining <= p) {
            u32 cum = e;
            for (int i = 0; i < bpl; ++i) {
                u32 h = hist[base + i];
                if (cum + h >= remaining) {
                    s_out[0] = (u32)(base + i);
                    s_out[1] = remaining - cum;
                    break;
                }
                cum += h;
            }
        }
    }
    __syncthreads();
}

// warp-aggregated push: returns slot if pred else -1. All active lanes call together.
__device__ __forceinline__ int wave_push(u32* ctr, bool pred) {
    u64 m = __ballot(pred);
    if (m == 0) return -1;
    int lane = threadIdx.x & 63;
    int leader = __ffsll((long long)m) - 1;
    u32 base = 0;
    if (lane == leader) base = atomicAdd(ctr, (u32)__popcll(m));
    base = (u32)__shfl((int)base, leader);
    return pred ? (int)(base + __popcll(m & ((1ull << lane) - 1ull))) : -1;
}

// ---------------- k_a: keys + packed(label,argmax,mant) | gt_best ----------------

__global__ void k_a(const float* __restrict__ cls, const float* __restrict__ gt,
                    u32* __restrict__ kd_g, u32* __restrict__ samp,
                    int* __restrict__ gt_best, double* __restrict__ acc,
                    u32* __restrict__ done) {
    __shared__ float4 g[NG];
    __shared__ float sv[256];
    __shared__ int si[256];
    int bid = blockIdx.x;

    if (bid == 0) {
        if (threadIdx.x < 2) acc[threadIdx.x] = 0.0;
        if (threadIdx.x == 2) *done = 0;
    }

    if (bid < NB_LAB) {
        int b = bid / 88, bx = bid % 88;
        if (threadIdx.x < NG) g[threadIdx.x] = ((const float4*)gt)[b * NG + threadIdx.x];
        __syncthreads();
        int n = bx * 256 + threadIdx.x;
        if (n >= N_ANCH) return;
        float ax1, ay1, ax2, ay2; anchor_corners(n, ax1, ay1, ax2, ay2);
        float best = -1.0f; int bi = 0;
        for (int gi = 0; gi < NG; ++gi) {
            float4 G = g[gi];
            float v = iou_f(G.x, G.y, G.z, G.w, ax1, ay1, ax2, ay2);
            if (v > best) { best = v; bi = gi; }  // first-max
        }
        int lab = -1;
        if (best < 0.3f) lab = 0;
        if (best >= 0.7f) lab = 1;
        bool inside = (ax1 >= 0.0f && ay1 >= 0.0f && ax2 <= 800.0f && ay2 <= 800.0f);
        // enc: 0 -> -1(outside), 1 -> 0, 2 -> 1, 3 -> -1(inside, immune to gt_best)
        int enc = inside ? 3 : (lab + 1);
        int t = b * N_ANCH + n;
        u32 mant = threefry_bits((u32)t) >> 9;   // 23-bit uniform mantissa
        samp[t] = (mant << 9) | ((u32)bi << 4) | (u32)enc;
        int a = n % NA_T, hw = n / NA_T;
        float score = cls[((size_t)b * 18 + 9 + a) * NPOS + hw];
        kd_g[t] = ~f32_sort_asc(score);          // asc key: smaller = higher score
    } else {
        int gid = bid - NB_LAB;
        int b = gid / NG, gi = gid % NG;
        float4 G = ((const float4*)gt)[b * NG + gi];
        float best = -1.0f; int bidx = N_ANCH;
        for (int d = 0; d < 9; ++d) {
            float w, h; anchor_dims(d, w, h);
            for (int k = threadIdx.x; k < NPOS; k += 256) {
                float cx = (float)(8 + 16 * (k / FHW));
                float cy = (float)(8 + 16 * (k % FHW));
                float x1 = cx - 0.5f * w, y1 = cy - 0.5f * h;
                float x2 = cx + 0.5f * w, y2 = cy + 0.5f * h;
                float v = iou_f(G.x, G.y, G.z, G.w, x1, y1, x2, y2);
                if (v > best) { best = v; bidx = d * NPOS + k; }
            }
        }
        sv[threadIdx.x] = best; si[threadIdx.x] = bidx;
        __syncthreads();
        for (int s = 128; s > 0; s >>= 1) {
            if (threadIdx.x < s) {
                float v2 = sv[threadIdx.x + s]; int i2 = si[threadIdx.x + s];
                if (v2 > sv[threadIdx.x] || (v2 == sv[threadIdx.x] && i2 < si[threadIdx.x])) {
                    sv[threadIdx.x] = v2; si[threadIdx.x] = i2;
                }
            }
            __syncthreads();
        }
        if (threadIdx.x == 0) gt_best[gid] = si[0];
    }
}

// ---------------- k_c: blocks 0-7 topk+NMS | blocks 8-15 sample+loss+final ----------------

__global__ void __launch_bounds__(1024) k_c(
    const u32* __restrict__ kd_g, const u32* __restrict__ samp,
    const int* __restrict__ gt_best,
    const float* __restrict__ pred, const float* __restrict__ cls,
    const float* __restrict__ gt, float* __restrict__ out,
    double* __restrict__ acc, int* __restrict__ cnt_out, u32* __restrict__ done)
{
    int tid = threadIdx.x;
    int lane = tid & 63, wid = tid >> 6;

    __shared__ u32 histA[4096];     // hists; later (u64*) sub-candidate buffer
    __shared__ u64 poolB[2048];     // topk: bin candidates / merge ping-pong / (x1,y1)
    __shared__ u64 sk[2048];        // topk: keys / merge ping-pong / (x2,y2) | sample: bufP/bufN
    __shared__ float4 accb[POST];
    __shared__ u64 Smat[64];
    __shared__ u64 wsup[16];
    __shared__ u32 s_out[2];
    __shared__ u32 s_cnt, s_cnt2, s_cnt3;
    __shared__ int s_scount;
    __shared__ int sgb[NG];
    __shared__ u64 sT, sTp, sTn;
    if (tid < 2) s_out[tid] = 0;

    if (blockIdx.x < BN) {
        // ================== TOPK + NMS (batch b) ==================
        int b = blockIdx.x;
        const u32* kb = kd_g + (size_t)b * N_ANCH;

        // scan 1: build 2048-bin hist over kd>>21 in LDS
        for (int i = tid; i < 2048; i += 1024) histA[i] = 0;
        __syncthreads();
        for (int c = 0; c < 22; ++c) {
            int n = tid + c * 1024;
            if (n < N_ANCH) atomicAdd(&histA[kb[n] >> 21], 1u);
        }
        __syncthreads();
        hist_pick(histA, 2048, PRE, s_out);
        u32 d0 = s_out[0], r0 = s_out[1];
        u32 bincnt = histA[d0];
        bool fast = bincnt <= 2048;

        // unique fillers (> any real 47-bit key) so merge stays collision-free
        for (int i = tid; i < 2048; i += 1024) sk[i] = 0xFFFFFFFFFFFFFFFFull - (u32)i;
        if (tid == 0) { s_cnt = 0; s_cnt2 = 0; }
        __syncthreads();

        // scan 2: below-bin keys -> sk, boundary-bin keys -> poolB
        for (int c = 0; c < 22; ++c) {
            int n = tid + c * 1024;
            bool valid = n < N_ANCH;
            u32 kd = valid ? kb[n] : 0xFFFFFFFFu;
            u64 kk = (((u64)kd) << 15) | (u32)(valid ? n : 0);
            u32 topb = kd >> 21;
            int ps = wave_push(&s_cnt, valid && topb < d0);
            if (ps >= 0) sk[ps] = kk;
            int pb = wave_push(&s_cnt2, valid && fast && topb == d0);
            if (pb >= 0) poolB[pb] = kk;
        }
        __syncthreads();
        int bc = (int)s_cnt2;

        u64 T;
        u64 prefix = ((u64)d0) << 36;
        if (fast) {
            // ONE 12-bit refine over the LDS bin buffer
            for (int i = tid; i < 4096; i += 1024) histA[i] = 0;
            __syncthreads();
            u64 himask = ~((1ull << 36) - 1);
            for (int i = tid; i < bc; i += 1024) {
                u64 kk = poolB[i];
                if ((kk & himask) == prefix)
                    atomicAdd(&histA[(u32)((kk >> 24) & 4095ull)], 1u);
            }
            __syncthreads();
            hist_pick(histA, 4096, r0, s_out);
            u64 prefix2 = prefix | (((u64)s_out[0]) << 24);
            u32 rem2 = s_out[1];
            __syncthreads();
            // gather the few keys sharing the 23-bit prefix; exact rank select
            u64* subb = (u64*)histA;     // 2048 u64 capacity >= bc
            if (tid == 0) s_cnt3 = 0;
            __syncthreads();
            u64 himask2 = ~((1ull << 24) - 1);
            for (int i = tid; i < bc; i += 1024) {
                u64 kk = poolB[i];
                int ps = wave_push(&s_cnt3, (kk & himask2) == prefix2);
                if (ps >= 0) subb[ps] = kk;
            }
            __syncthreads();
            int sc = (int)s_cnt3;
            for (int i = tid; i < sc; i += 1024) {
                u64 ki = subb[i]; int rank = 0;
                for (int j = 0; j < sc; ++j) rank += (subb[j] < ki);
                if (rank == (int)rem2 - 1) sT = ki;
            }
            __syncthreads();
            T = sT;
            // append bin keys <= T
            for (int i = tid; i < bc; i += 1024) {
                u64 kk = poolB[i];
                int ps = wave_push(&s_cnt, kk <= T);
                if (ps >= 0) sk[ps] = kk;
            }
        } else {
            // fallback: 3 x 12-bit global refine passes (adversarial huge bin)
            u32 remaining = r0;
            for (int p = 0; p < 3; ++p) {
                int sh = 24 - 12 * p;
                for (int i = tid; i < 4096; i += 1024) histA[i] = 0;
                __syncthreads();
                u64 himask = ~((1ull << (sh + 12)) - 1);
                for (int c = 0; c < 22; ++c) {
                    int n = tid + c * 1024;
                    if (n < N_ANCH) {
                        u64 kk = (((u64)kb[n]) << 15) | (u32)n;
                        if ((kk & himask) == prefix)
                            atomicAdd(&histA[(u32)((kk >> sh) & 4095ull)], 1u);
                    }
                }
                __syncthreads();
                hist_pick(histA, 4096, remaining, s_out);
                prefix |= ((u64)s_out[0]) << sh;
                remaining = s_out[1];
                __syncthreads();
            }
            T = prefix;
            for (int c = 0; c < 22; ++c) {
                int n = tid + c * 1024;
                bool valid = n < N_ANCH;
                u32 kd = valid ? kb[n] : 0xFFFFFFFFu;
                u64 kk = (((u64)kd) << 15) | (u32)(valid ? n : 0);
                int ps = wave_push(&s_cnt, valid && (kd >> 21) == d0 && kk <= T);
                if (ps >= 0) sk[ps] = kk;
            }
        }
        __syncthreads();

        // ---- per-wave register bitonic sort of 128 keys (no barriers) ----
        {
            int base = wid * 128;
            u64 v0 = sk[base + lane];
            u64 v1 = sk[base + 64 + lane];
            for (int k = 2; k <= 128; k <<= 1) {
                bool up0 = ((lane & k) == 0);            // e0 = lane
                bool up1 = (((64 + lane) & k) == 0);     // e1 = 64+lane
                for (int j = k >> 1; j > 0; j >>= 1) {
                    if (j == 64) {                        // only k==128: cross-reg pair
                        u64 lo = v0 < v1 ? v0 : v1;
                        u64 hi = v0 < v1 ? v1 : v0;
                        v0 = lo; v1 = hi;                 // up0==up1==true here
                    } else {
                        u64 p0 = shflx64(v0, j);
                        u64 p1 = shflx64(v1, j);
                        bool lower = ((lane & j) == 0);
                        bool km0 = (lower == up0);
                        bool km1 = (lower == up1);
                        v0 = km0 ? (v0 < p0 ? v0 : p0) : (v0 > p0 ? v0 : p0);
                        v1 = km1 ? (v1 < p1 ? v1 : p1) : (v1 > p1 ? v1 : p1);
                    }
                }
            }
            sk[base + lane] = v0;
            sk[base + 64 + lane] = v1;
        }
        __syncthreads();

        // ---- 4 rank-merge rounds: 16 sorted runs of 128 -> one of 2048 ----
        {
            u64* src = sk; u64* dst = poolB;
            for (int S = 128; S < 2048; S <<= 1) {
                for (int e = 0; e < 2; ++e) {
                    int i = tid + e * 1024;
                    u64 key = src[i];
                    int pairBase = i & ~(2 * S - 1);
                    int t = i - pairBase;
                    const u64* other; int p;
                    if (t < S) { other = src + pairBase + S; p = t; }
                    else       { other = src + pairBase;     p = t - S; }
                    int lo = 0, hi = S;
                    while (lo < hi) {
                        int mid = (lo + hi) >> 1;
                        if (other[mid] < key) lo = mid + 1; else hi = mid;
                    }
                    dst[pairBase + p + lo] = key;
                }
                __syncthreads();
                u64* tmp = src; src = dst; dst = tmp;
            }
            // 4 rounds: sk->poolB->sk->poolB->sk ; sorted result in sk
        }

        // recompute proposal boxes for the sorted 2000 (bit-identical math)
        float2* bl = (float2*)poolB;
        float2* bh = (float2*)sk;
        for (int i = tid; i < 2048; i += 1024) {
            float2 lo = make_float2(0.f, 0.f), hi = make_float2(0.f, 0.f);
            if (i < PRE) {
                int n = (int)(sk[i] & 0x7fffu);
                float ax1, ay1, ax2, ay2; anchor_corners(n, ax1, ay1, ax2, ay2);
                float acx = (ax1 + ax2) * 0.5f, acy = (ay1 + ay2) * 0.5f;
                float aw = ax2 - ax1, ah = ay2 - ay1;
                int a = n % NA_T, hw = n / NA_T;
                const float* pb = pred + (size_t)b * 36 * NPOS;
                float dx = pb[(4 * a + 0) * NPOS + hw];
                float dy = pb[(4 * a + 1) * NPOS + hw];
                float dw = pb[(4 * a + 2) * NPOS + hw];
                float dh = pb[(4 * a + 3) * NPOS + hw];
                float px = acx + dx * aw, py = acy + dy * ah;
                float pw = aw * expf(dw), ph = ah * expf(dh);
                float x1 = px - 0.5f * pw, y1 = py - 0.5f * ph;
                float x2 = px + 0.5f * pw, y2 = py + 0.5f * ph;
                x1 = fminf(fmaxf(x1, 0.0f), 799.0f);
                y1 = fminf(fmaxf(y1, 0.0f), 799.0f);
                x2 = fminf(fmaxf(x2, 0.0f), 799.0f);
                y2 = fminf(fmaxf(y2, 0.0f), 799.0f);
                lo = make_float2(x1, y1); hi = make_float2(x2, y2);
            }
            bl[i] = lo; bh[i] = hi;
        }
        if (tid == 0) s_scount = 0;
        __syncthreads();

        // ---- on-the-fly greedy NMS (register Smat + shfl accept chain) ----
        for (int c = 0; c < 32; ++c) {
            int A = s_scount;
            int base = c * 64;
            float2 clo = bl[base + lane], chi = bh[base + lane];
            bool sup = false;
            for (int a = wid; a < A; a += 16) {
                float4 ab = accb[a];
                sup |= iou_f(ab.x, ab.y, ab.z, ab.w, clo.x, clo.y, chi.x, chi.y) > 0.7f;
            }
            u64 bal = __ballot(sup);
            if (lane == 0) wsup[wid] = bal;
            #pragma unroll
            for (int q = 0; q < 4; ++q) {
                int o = wid * 4 + q;
                float2 olo = bl[base + o], ohi = bh[base + o];
                bool hit = iou_f(olo.x, olo.y, ohi.x, ohi.y, clo.x, clo.y, chi.x, chi.y) > 0.7f;
                u64 m = __ballot(hit);
                if (lane == 0) Smat[o] = m;
            }
            __syncthreads();
            if (wid == 0) {
                u64 my_smat = Smat[lane];
                u64 supmask = 0;
                #pragma unroll
                for (int i2 = 0; i2 < 16; ++i2) supmask |= wsup[i2];
                int jmax = min(64, PRE - base);
                u64 valid = (jmax >= 64) ? ~0ull : ((1ull << jmax) - 1ull);
                u64 live = (~supmask) & valid;
                int count = A;
                while (live && count < POST) {
                    int i = __ffsll((long long)live) - 1;
                    u64 sm = shfl64(my_smat, i);
                    if (lane == i) accb[count] = make_float4(clo.x, clo.y, chi.x, chi.y);
                    live &= ~sm & ~(1ull << i);
                    count++;
                }
                if (lane == 0) s_scount = count;
            }
            __syncthreads();
            if (s_scount >= POST) break;
        }
        int cntk = s_scount;
        for (int s = tid; s < POST; s += 1024) {
            float4 v = make_float4(0.f, 0.f, 0.f, 0.f);
            if (s < cntk) {
                float4 p = accb[s];
                v = make_float4(floorf(p.x), floorf(p.y), floorf(p.z), floorf(p.w));
            }
            ((float4*)out)[(size_t)b * POST + s] = v;
        }
    } else {
        // ================== SAMPLE + LOSS (batch b) ==================
        int b = blockIdx.x - BN;
        u32* bitmap = (u32*)poolB;        // 704 u32 = 2816 B
        u64* sred   = poolB + 512;        // byte offset 4096, clear of bitmap
        u32* hP = histA;                  // 2048
        u32* hN = histA + 2048;           // 2048
        u64* bufP = sk;                   // 1024
        u64* bufN = sk + 1024;            // 1024
        const u32* sb = samp + (size_t)b * N_ANCH;

        for (int i = tid; i < 704; i += 1024) bitmap[i] = 0;
        for (int i = tid; i < 4096; i += 1024) histA[i] = 0;
        if (tid < NG) sgb[tid] = gt_best[b * NG + tid];
        __syncthreads();

        // scan 1: build pos/neg mantissa hists in LDS; set gt_best bitmap
        for (int c = 0; c < 22; ++c) {
            int n = tid + c * 1024;
            if (n < N_ANCH) {
                u32 sp = sb[n];
                int enc = (int)(sp & 3u);
                if (enc == 2) atomicAdd(&hP[sp >> 21], 1u);
                if (enc == 1) atomicAdd(&hN[sp >> 21], 1u);
            }
        }
        if (tid < NG) {
            int gn = sgb[tid];
            atomicOr(&bitmap[gn >> 5], 1u << (gn & 31));
        }
        __syncthreads();
        if (tid < NG) {
            int gn = sgb[tid];
            bool dup = false;
            for (int j = 0; j < tid; ++j) dup |= (sgb[j] == gn);
            if (!dup) {
                // apply gt_best promotion to hists (rank-exact correction)
                u32 sp = sb[gn];
                int enc = (int)(sp & 3u);
                if (enc != 3) {               // inside anchors stay -1
                    if (enc != 2) atomicAdd(&hP[sp >> 21], 1u);
                    if (enc == 1) atomicSub(&hN[sp >> 21], 1u);
                }
            }
        }
        __syncthreads();

        u32 aP = 0, aN = 0;
        for (int i = tid; i < 2048; i += 1024) { aP += hP[i]; aN += hN[i]; }
        u64 packed = block_sum_u64(((u64)aP << 32) | (u64)aN, sred, 16);
        int cpt = (int)(packed >> 32), ctot = (int)(packed & 0xffffffffu);
        int np = min(cpt, 128), nn = min(ctot, 256 - np);

        bool needP = cpt > np, needN = ctot > nn;
        u32 dP = 0, remP = 0, dN = 0, remN = 0;
        if (needP) {
            hist_pick(hP, 2048, (u32)np, s_out);
            dP = s_out[0]; remP = s_out[1];
            __syncthreads();
        }
        if (needN) {
            hist_pick(hN, 2048, (u32)nn, s_out);
            dN = s_out[0]; remN = s_out[1];
            __syncthreads();
        }

        if (tid == 0) { s_cnt = 0; s_cnt2 = 0; }
        __syncthreads();

        // scan 2: gather boundary-bin candidates for pos and neg
        for (int c = 0; c < 22; ++c) {
            int n = tid + c * 1024;
            bool valid = n < N_ANCH;
            u32 sp = valid ? sb[n] : 0u;
            int enc = (int)(sp & 3u);
            bool bm = valid && ((bitmap[n >> 5] >> (n & 31)) & 1u);
            int l = (enc == 3) ? -1 : (bm ? 1 : enc - 1);
            u64 kk = (((u64)(sp >> 9)) << 15) | (u32)(valid ? n : 0);
            int pp = wave_push(&s_cnt, valid && needP && l == 1 && (sp >> 21) == dP);
            if (pp >= 0 && pp < 1024) bufP[pp] = kk;
            int pn = wave_push(&s_cnt2, valid && needN && l == 0 && (sp >> 21) == dN);
            if (pn >= 0 && pn < 1024) bufN[pn] = kk;
        }
        __syncthreads();

        // tiny exact rank-select within each boundary bin (O(cnt^2), cnt ~ 10)
        if (needP) {
            int cnt = min((int)s_cnt, 1024);
            for (int i = tid; i < cnt; i += 1024) {
                u64 ki = bufP[i]; int rank = 0;
                for (int j = 0; j < cnt; ++j) rank += (bufP[j] < ki);
                if (rank == (int)remP - 1) sTp = ki;
            }
        }
        if (needN) {
            int cnt = min((int)s_cnt2, 1024);
            for (int i = tid; i < cnt; i += 1024) {
                u64 ki = bufN[i]; int rank = 0;
                for (int j = 0; j < cnt; ++j) rank += (bufN[j] < ki);
                if (rank == (int)remN - 1) sTn = ki;
            }
        }
        __syncthreads();
        u64 Tp = needP ? sTp : ~0ull;
        u64 Tn = needN ? sTn : ~0ull;

        // loss over selected samples
        double lcls = 0.0, lbox = 0.0;
        #pragma unroll
        for (int c = 0; c < 22; ++c) {
            int n = tid + c * 1024;
            if (n >= N_ANCH) continue;
            u32 sp = sb[n];
            int enc = (int)(sp & 3u);
            bool bm = (bitmap[n >> 5] >> (n & 31)) & 1u;
            int l = (enc == 3) ? -1 : (bm ? 1 : enc - 1);
            if (l < 0) continue;
            u64 kk = (((u64)(sp >> 9)) << 15) | (u32)n;
            int lab = -1;
            if (l == 1) { if (kk <= Tp) lab = 1; }
            else        { if (kk <= Tn) lab = 0; }
            if (lab < 0) continue;
            int a = n % NA_T, hw = n / NA_T;
            float l0 = cls[((size_t)b * 18 + 2 * a + 0) * NPOS + hw];
            float l1 = cls[((size_t)b * 18 + 2 * a + 1) * NPOS + hw];
            float m = fmaxf(l0, l1);
            float s0 = l0 - m, s1 = l1 - m;
            float lse = logf(expf(s0) + expf(s1));
            lcls += (double)(-((lab ? s1 : s0) - lse));
            if (lab == 1) {
                const float* pb = pred + (size_t)b * 36 * NPOS;
                float dx = pb[(4 * a + 0) * NPOS + hw];
                float dy = pb[(4 * a + 1) * NPOS + hw];
                float dw = pb[(4 * a + 2) * NPOS + hw];
                float dh = pb[(4 * a + 3) * NPOS + hw];
                float ax1, ay1, ax2, ay2; anchor_corners(n, ax1, ay1, ax2, ay2);
                float acx = (ax1 + ax2) * 0.5f, acy = (ay1 + ay2) * 0.5f;
                float aw = ax2 - ax1, ah = ay2 - ay1;
                float4 G = ((const float4*)gt)[b * NG + ((sp >> 4) & 31u)];
                float gcx = (G.x + G.z) * 0.5f, gcy = (G.y + G.w) * 0.5f;
                float gw = G.z - G.x, gh = G.w - G.y;
                float t0 = (gcx - acx) / aw, t1 = (gcy - acy) / ah;
                float t2 = logf(gw / aw), t3 = logf(gh / ah);
                lbox += (double)(smooth_l1(dx - t0) + smooth_l1(dy - t1) +
                                 smooth_l1(dw - t2) + smooth_l1(dh - t3));
            }
        }
        for (int o = 32; o >= 1; o >>= 1) {
            lcls += __shfl_down(lcls, o);
            lbox += __shfl_down(lbox, o);
        }
        if ((tid & 63) == 0) {
            atomicAdd(&acc[0], lcls);
            atomicAdd(&acc[1], lbox);
        }
        if (tid == 0) cnt_out[b] = np + nn;
        __syncthreads();

        if (tid == 0) {
            __threadfence();
            u32 r = atomicAdd(done, 1u);
            if (r == BN - 1) {
                __threadfence();
                volatile double* va = (volatile double*)acc;
                volatile int* vc = (volatile int*)cnt_out;
                double a0 = va[0], a1 = va[1];
                int total = 0, c0 = 0;
                for (int bb = 0; bb < BN; ++bb) {
                    int v = vc[bb];
                    total += v;
                    if (bb == 0) c0 = v;
                }
                out[BN * POST * 4 + 0] = (float)(a1 / (double)max(c0, 1));     // bbox_loss
                out[BN * POST * 4 + 1] = (float)(a0 / (double)max(total, 1));  // cls_loss
            }
        }
    }
}

// ---------------- launch ----------------

extern "C" void kernel_launch(void* const* d_in, const int* in_sizes, int n_in,
                              void* d_out, int out_size, void* d_ws, size_t ws_size,
                              hipStream_t stream) {
    (void)in_sizes; (void)n_in; (void)out_size; (void)ws_size;
    const float* pred = (const float*)d_in[0];   // (8,36,50,50)
    const float* cls  = (const float*)d_in[1];   // (8,18,50,50)
    const float* gt   = (const float*)d_in[2];   // (8,20,4)
    float* out = (float*)d_out;                  // 9600 boxes + 2 losses

    char* w = (char*)d_ws;
    size_t off = 0;
    auto take = [&](size_t bytes) { void* p = w + off; off += (bytes + 255) & ~(size_t)255; return p; };
    u32* kd_g    = (u32*)take((size_t)TOTAL * 4);        // 720 KB
    u32* samp    = (u32*)take((size_t)TOTAL * 4);        // 720 KB (mant|argmax|label)
    int* gt_best = (int*)take((size_t)BN * NG * 4);
    int* cnt_out = (int*)take(BN * 4);
    double* acc  = (double*)take(2 * 8);
    u32* done    = (u32*)take(4);

    k_a<<<NB_LAB + NB_GTB, 256, 0, stream>>>(cls, gt, kd_g, samp, gt_best, acc, done);
    k_c<<<2 * BN, 1024, 0, stream>>>(kd_g, samp, gt_best, pred, cls, gt,
                                     out, acc, cnt_out, done);
}